// Round 1
// baseline (321.207 us; speedup 1.0000x reference)
//
#include <hip/hip_runtime.h>

// TSK fuzzy model forward.  N=32768 rows, D=64 dims, R=32 rules.
// R5 experiment: SPLIT into compute kernel (w,y) + fill-shaped Phi streamer.
// Evidence: harness fill dispatch writes 1.08 GB @ 5.9 TB/s (~188 us of the
// 300.9 us timed region); the fused kernel's remainder (~113 us for ~285 MB)
// ran at only ~2.5 TB/s.  Theory: 25 KB/block constant staging + 2 barriers +
// 5-blocks/CU LDS cap coupled the store stream to the compute structure.
// The streamer below stages 3.3 KB/block, one barrier, then pure float4
// stores -- structurally identical to the 5.9 TB/s fill kernel.
// Outputs concatenated flat: y[N], w[N*R], Phi[N*R*(D+1)]  (fp32, proven R4:
// bf16 packing fails the 2%-of-refmax threshold).

constexpr int N_ROWS = 32768;
constexpr int D = 64;
constexpr int R = 32;
constexpr float EPS = 1e-12f;
constexpr int PHI_COLS = R * (D + 1);  // 2080

// ---------------- Kernel A: w + y (compute-heavy, tiny traffic) ----------
constexpr int A_ROWS = 32;   // rows per block: amortize 25 KB constant stage
constexpr int A_BLOCK = 256;

__global__ __launch_bounds__(A_BLOCK) void wy_kernel(
    const float* __restrict__ Xz,
    const float* __restrict__ centers,
    const float* __restrict__ sigmas,
    const float* __restrict__ theta,
    float* __restrict__ y_out,
    float* __restrict__ w_out)
{
    // stride 65 -> bank (r+d)%32: conflict-free when 32 lanes sweep r at fixed d
    __shared__ float c_lds[R][D + 1];
    __shared__ float is_lds[R][D + 1];
    __shared__ float th_lds[R][D + 1];
    __shared__ float x_lds[A_ROWS][D + 1];

    const int tid = threadIdx.x;
    const int row0 = blockIdx.x * A_ROWS;

    // ---- stage constants (inv-sigma precomputed) ----
    for (int i = tid; i < R * D; i += A_BLOCK) {
        int r = i >> 6, d = i & 63;
        c_lds[r][d] = centers[i];
        is_lds[r][d] = 1.0f / (sigmas[i] + EPS);
    }
    for (int i = tid; i < R * (D + 1); i += A_BLOCK)
        th_lds[i / 65][i % 65] = theta[i];

    // ---- stage 32 rows of x: 2048 floats = 512 float4 ----
    {
        const float4* x4 = (const float4*)(Xz + (size_t)row0 * D);
#pragma unroll
        for (int t = tid; t < A_ROWS * D / 4; t += A_BLOCK) {
            float4 v = x4[t];
            int e = 4 * t;
            int rr = e >> 6, cc = e & 63;
            x_lds[rr][cc]     = v.x;
            x_lds[rr][cc + 1] = v.y;
            x_lds[rr][cc + 2] = v.z;
            x_lds[rr][cc + 3] = v.w;
        }
    }
    __syncthreads();

    const int r = tid & 31;      // rule lane
#pragma unroll
    for (int sub = 0; sub < A_ROWS / 8; ++sub) {
        const int lrow = sub * 8 + (tid >> 5);
        float acc = 0.0f;
        float tdot = th_lds[r][0];
#pragma unroll
        for (int d = 0; d < D; ++d) {
            float x = x_lds[lrow][d];
            float z = (x - c_lds[r][d]) * is_lds[r][d];
            acc = fmaf(z, z, acc);
            tdot = fmaf(th_lds[r][d + 1], x, tdot);
        }
        float logw = -0.5f * acc;

        // softmax over the 32 rule-lanes of this row
        float m = logw;
#pragma unroll
        for (int off = 16; off >= 1; off >>= 1)
            m = fmaxf(m, __shfl_xor(m, off, 32));
        float ex = __expf(logw - m);
        float s = ex;
#pragma unroll
        for (int off = 16; off >= 1; off >>= 1)
            s += __shfl_xor(s, off, 32);
        float w = ex / (s + EPS);
        w_out[(size_t)(row0 + lrow) * R + r] = w;

        // y = sum_r w_r * (theta_r . [1,x])
        float yc = w * tdot;
#pragma unroll
        for (int off = 16; off >= 1; off >>= 1)
            yc += __shfl_xor(yc, off, 32);
        if (r == 0) y_out[row0 + lrow] = yc;
    }
}

// ---------------- Kernel B: Phi streamer (fill-shaped) --------------------
constexpr int B_ROWS = 8;
constexpr int B_BLOCK = 256;

__global__ __launch_bounds__(B_BLOCK, 8) void phi_kernel(
    const float* __restrict__ Xz,
    const float* __restrict__ w_in,
    float* __restrict__ phi_out)
{
    // x1[row] = [1, x0..x63]; leading 1 removes the per-element (j==0) select.
    __shared__ float x1_lds[B_ROWS][66];
    __shared__ float w_lds[B_ROWS][R + 1];

    const int tid = threadIdx.x;
    const int row0 = blockIdx.x * B_ROWS;

    // stage 8 rows of x (512 floats = 128 float4) into columns 1..64
    if (tid < 128) {
        const float4* x4 = (const float4*)(Xz + (size_t)row0 * D);
        float4 v = x4[tid];
        int e = 4 * tid;
        int rr = e >> 6, cc = (e & 63) + 1;
        x1_lds[rr][cc]     = v.x;
        x1_lds[rr][cc + 1] = v.y;
        x1_lds[rr][cc + 2] = v.z;
        x1_lds[rr][cc + 3] = v.w;
    }
    // stage 8 rows of w (256 floats = 64 float4)
    if (tid < 64) {
        const float4* w4 = (const float4*)(w_in + (size_t)row0 * R);
        float4 v = w4[tid];
        int e = 4 * tid;
        int rr = e >> 5, cc = e & 31;
        w_lds[rr][cc]     = v.x;
        w_lds[rr][cc + 1] = v.y;
        w_lds[rr][cc + 2] = v.z;
        w_lds[rr][cc + 3] = v.w;
    }
    if (tid < B_ROWS) x1_lds[tid][0] = 1.0f;
    __syncthreads();

    // stream Phi as float4 (16 B/lane): lane k writes quad k of each row ->
    // 64 lanes x 16 B = 1 KB contiguous per store instruction.
    // phi_out base byte offset 4,325,376 and row stride 8320 B are 16B-aligned.
    for (int k = tid; k < PHI_COLS / 4; k += B_BLOCK) {
        int e = 4 * k;
        int r0 = (e + 0) / 65, j0 = (e + 0) - r0 * 65;
        int r1 = (e + 1) / 65, j1 = (e + 1) - r1 * 65;
        int r2 = (e + 2) / 65, j2 = (e + 2) - r2 * 65;
        int r3 = (e + 3) / 65, j3 = (e + 3) - r3 * 65;
#pragma unroll
        for (int row = 0; row < B_ROWS; ++row) {
            float4 o;
            o.x = w_lds[row][r0] * x1_lds[row][j0];
            o.y = w_lds[row][r1] * x1_lds[row][j1];
            o.z = w_lds[row][r2] * x1_lds[row][j2];
            o.w = w_lds[row][r3] * x1_lds[row][j3];
            ((float4*)(phi_out + (size_t)(row0 + row) * PHI_COLS))[k] = o;
        }
    }
}

extern "C" void kernel_launch(void* const* d_in, const int* in_sizes, int n_in,
                              void* d_out, int out_size, void* d_ws, size_t ws_size,
                              hipStream_t stream) {
    const float* Xz      = (const float*)d_in[0];
    const float* centers = (const float*)d_in[1];
    const float* sigmas  = (const float*)d_in[2];
    const float* theta   = (const float*)d_in[3];

    float* out = (float*)d_out;
    float* y_out   = out;
    float* w_out   = out + N_ROWS;
    float* phi_out = out + N_ROWS + (size_t)N_ROWS * R;

    wy_kernel<<<dim3(N_ROWS / A_ROWS), A_BLOCK, 0, stream>>>(
        Xz, centers, sigmas, theta, y_out, w_out);
    phi_kernel<<<dim3(N_ROWS / B_ROWS), B_BLOCK, 0, stream>>>(
        Xz, w_out, phi_out);
}

// Round 2
// 304.063 us; speedup vs baseline: 1.0564x; 1.0564x over previous
//
#include <hip/hip_runtime.h>

// TSK fuzzy model forward.  N=32768 rows, D=64 dims, R=32 rules.
// R6: fused structure REVERTED to the proven 300.9us kernel (R5 split
// regressed to 321us: a fill-shaped pure streamer ran at the same ~2.4 TB/s
// as the fused store phase -> block structure is NOT the limiter).
// Single-variable experiment this round: NONTEMPORAL stores on the Phi/w/y
// streams.  Theory: TCC write-allocate/RFO fetches ~273 MB hidden FETCH for
// the streamed output (285 MB moved in 113us = 2.4 TB/s, but 285+273 MB in
// 113us = 5.9 TB/s = exactly the fill kernel's demonstrated rate).  nt
// stores bypass L2 allocation and stream to HBM.
// Outputs concatenated flat: y[N], w[N*R], Phi[N*R*(D+1)]  (fp32, proven R4:
// bf16 packing fails the 2%-of-refmax threshold).

constexpr int N_ROWS = 32768;
constexpr int D = 64;
constexpr int R = 32;
constexpr float EPS = 1e-12f;
constexpr int ROWS_PER_BLOCK = 8;
constexpr int BLOCK = 256;
constexpr int PHI_COLS = R * (D + 1);  // 2080

typedef float f32x4 __attribute__((ext_vector_type(4)));

__global__ __launch_bounds__(BLOCK) void tsk_kernel(
    const float* __restrict__ Xz,
    const float* __restrict__ centers,
    const float* __restrict__ sigmas,
    const float* __restrict__ theta,
    float* __restrict__ y_out,
    float* __restrict__ w_out,
    float* __restrict__ phi_out)
{
    // stride 65 -> bank (r+d)%32: conflict-free when 32 lanes sweep r at fixed d
    __shared__ float c_lds[R][D + 1];
    __shared__ float is_lds[R][D + 1];
    __shared__ float th_lds[R][D + 1];
    // x1[row] = [1, x0..x63]: leading 1 removes the per-element (j==0) select
    __shared__ float x1_lds[ROWS_PER_BLOCK][D + 2];
    __shared__ float w_lds[ROWS_PER_BLOCK][R + 1];

    const int tid = threadIdx.x;
    const int row0 = blockIdx.x * ROWS_PER_BLOCK;

    // ---- stage constants into LDS (inv-sigma precomputed) ----
    for (int i = tid; i < R * D; i += BLOCK) {
        int r = i >> 6, d = i & 63;
        c_lds[r][d] = centers[i];
        is_lds[r][d] = 1.0f / (sigmas[i] + EPS);
    }
    for (int i = tid; i < R * (D + 1); i += BLOCK)
        th_lds[i / 65][i % 65] = theta[i];

    // ---- stage this block's 8 rows of x: 512 floats = 128 float4 ----
    if (tid < 128) {
        const f32x4* x4 = (const f32x4*)(Xz + (size_t)row0 * D);
        f32x4 v = x4[tid];
        int e = 4 * tid;                 // 0..508
        int rr = e >> 6, cc = (e & 63) + 1;
        x1_lds[rr][cc]     = v.x;
        x1_lds[rr][cc + 1] = v.y;
        x1_lds[rr][cc + 2] = v.z;
        x1_lds[rr][cc + 3] = v.w;
    }
    if (tid < ROWS_PER_BLOCK) x1_lds[tid][0] = 1.0f;
    __syncthreads();

    // ---- phase 1: thread = (local_row, rule) ----
    const int lrow = tid >> 5;   // 0..7
    const int r = tid & 31;      // 0..31
    float acc = 0.0f;
    float tdot = th_lds[r][0];
#pragma unroll
    for (int d = 0; d < D; ++d) {
        float x = x1_lds[lrow][d + 1];
        float z = (x - c_lds[r][d]) * is_lds[r][d];
        acc = fmaf(z, z, acc);
        tdot = fmaf(th_lds[r][d + 1], x, tdot);
    }
    float logw = -0.5f * acc;

    // softmax over the 32 rule-lanes of this row
    float m = logw;
#pragma unroll
    for (int off = 16; off >= 1; off >>= 1)
        m = fmaxf(m, __shfl_xor(m, off, 32));
    float ex = __expf(logw - m);
    float s = ex;
#pragma unroll
    for (int off = 16; off >= 1; off >>= 1)
        s += __shfl_xor(s, off, 32);
    float w = ex / (s + EPS);
    w_lds[lrow][r] = w;
    __builtin_nontemporal_store(w, w_out + (size_t)(row0 + lrow) * R + r);

    // y = sum_r w_r * (theta_r . [1,x])
    float yc = w * tdot;
#pragma unroll
    for (int off = 16; off >= 1; off >>= 1)
        yc += __shfl_xor(yc, off, 32);
    if (r == 0) __builtin_nontemporal_store(yc, y_out + row0 + lrow);
    __syncthreads();

    // ---- phase 2: stream Phi as float4 (16 B/lane), fully coalesced ----
    // phi_out base byte offset 4,325,376 and row stride 8320 B are both
    // 128B-aligned; each wave's store covers 1 KB contiguous (full lines).
    // nt stores: bypass L2 allocation (the experiment).
    for (int k = tid; k < PHI_COLS / 4; k += BLOCK) {
        int e = 4 * k;
        int r0 = (e + 0) / 65, j0 = (e + 0) - r0 * 65;
        int r1 = (e + 1) / 65, j1 = (e + 1) - r1 * 65;
        int r2 = (e + 2) / 65, j2 = (e + 2) - r2 * 65;
        int r3 = (e + 3) / 65, j3 = (e + 3) - r3 * 65;
#pragma unroll
        for (int row = 0; row < ROWS_PER_BLOCK; ++row) {
            f32x4 o;
            o.x = w_lds[row][r0] * x1_lds[row][j0];
            o.y = w_lds[row][r1] * x1_lds[row][j1];
            o.z = w_lds[row][r2] * x1_lds[row][j2];
            o.w = w_lds[row][r3] * x1_lds[row][j3];
            f32x4* dst = (f32x4*)(phi_out + (size_t)(row0 + row) * PHI_COLS) + k;
            __builtin_nontemporal_store(o, dst);
        }
    }
}

extern "C" void kernel_launch(void* const* d_in, const int* in_sizes, int n_in,
                              void* d_out, int out_size, void* d_ws, size_t ws_size,
                              hipStream_t stream) {
    const float* Xz      = (const float*)d_in[0];
    const float* centers = (const float*)d_in[1];
    const float* sigmas  = (const float*)d_in[2];
    const float* theta   = (const float*)d_in[3];

    float* out = (float*)d_out;
    float* y_out   = out;
    float* w_out   = out + N_ROWS;
    float* phi_out = out + N_ROWS + (size_t)N_ROWS * R;

    dim3 grid(N_ROWS / ROWS_PER_BLOCK);
    tsk_kernel<<<grid, BLOCK, 0, stream>>>(Xz, centers, sigmas, theta,
                                           y_out, w_out, phi_out);
}

// Round 3
// 294.483 us; speedup vs baseline: 1.0908x; 1.0325x over previous
//
#include <hip/hip_runtime.h>

// TSK fuzzy model forward.  N=32768 rows, D=64 dims, R=32 rules.
// R7: phase-1 LDS reads vectorized to ds_read_b128.
// History: R5 split FAILED (321us: fill-shaped streamer also ran 2.4 TB/s ->
// structure not the limiter).  R6 nt stores NEUTRAL (304us -> no RFO; TCC
// write-combines full-line stores).  New arithmetic: phase 1 issued 256
// scalar ds_read_b32/wave (c,is,th,x per d); at 5.8 cyc measured throughput
// that is ~40us/CU of LDS-pipe serialization -- the real bottleneck next to
// the 44us store-BW floor.  b128 reads (stride-68 padded rows, 16B-aligned)
// cut phase-1 LDS cycles ~3.5x.
// Outputs concatenated flat: y[N], w[N*R], Phi[N*R*(D+1)]  (fp32, proven R4:
// bf16 packing fails the 2%-of-refmax threshold).

constexpr int N_ROWS = 32768;
constexpr int D = 64;
constexpr int R = 32;
constexpr float EPS = 1e-12f;
constexpr int ROWS_PER_BLOCK = 8;
constexpr int BLOCK = 256;
constexpr int PHI_COLS = R * (D + 1);  // 2080
constexpr int CSTR = 68;   // constant-row stride (17 float4, 16B-aligned rows)
constexpr int XSTR = 72;   // x-row stride; 1.0 at col 3, x at cols 4..67

typedef float f32x4 __attribute__((ext_vector_type(4)));

__global__ __launch_bounds__(BLOCK) void tsk_kernel(
    const float* __restrict__ Xz,
    const float* __restrict__ centers,
    const float* __restrict__ sigmas,
    const float* __restrict__ theta,
    float* __restrict__ y_out,
    float* __restrict__ w_out,
    float* __restrict__ phi_out)
{
    // stride 68 dwords: rows 16B-aligned for b128; 32 rule-rows x 16B spread
    // exactly 4 dwords per bank per read -> conflict-free floor.
    __shared__ __align__(16) float c_lds[R][CSTR];
    __shared__ __align__(16) float is_lds[R][CSTR];
    __shared__ __align__(16) float th_lds[R][CSTR];   // theta[r][d+1], d=0..63
    __shared__ float th0_lds[R];                      // theta[r][0]
    // x1 row = [_,_,_,1, x0..x63]: col 3+j gives [1,x] with b128-aligned x
    __shared__ __align__(16) float x1_lds[ROWS_PER_BLOCK][XSTR];
    __shared__ float w_lds[ROWS_PER_BLOCK][R + 1];

    const int tid = threadIdx.x;
    const int row0 = blockIdx.x * ROWS_PER_BLOCK;

    // ---- stage constants into LDS (inv-sigma precomputed) ----
    for (int i = tid; i < R * D; i += BLOCK) {
        int r = i >> 6, d = i & 63;
        c_lds[r][d] = centers[i];
        is_lds[r][d] = 1.0f / (sigmas[i] + EPS);
        th_lds[r][d] = theta[r * (D + 1) + d + 1];
    }
    if (tid < R) th0_lds[tid] = theta[tid * (D + 1)];

    // ---- stage this block's 8 rows of x: 512 floats = 128 float4 ----
    if (tid < 128) {
        const f32x4* x4 = (const f32x4*)(Xz + (size_t)row0 * D);
        f32x4 v = x4[tid];
        int e = 4 * tid;                 // 0..508
        int rr = e >> 6, cc = (e & 63) + 4;   // cols 4..67, 16B-aligned
        *(f32x4*)&x1_lds[rr][cc] = v;
    }
    if (tid < ROWS_PER_BLOCK) x1_lds[tid][3] = 1.0f;
    __syncthreads();

    // ---- phase 1: thread = (local_row, rule); b128 LDS reads ----
    const int lrow = tid >> 5;   // 0..7
    const int r = tid & 31;      // 0..31
    float acc = 0.0f;
    float tdot = th0_lds[r];
#pragma unroll
    for (int q = 0; q < D / 4; ++q) {
        f32x4 cv = *(const f32x4*)&c_lds[r][4 * q];
        f32x4 iv = *(const f32x4*)&is_lds[r][4 * q];
        f32x4 tv = *(const f32x4*)&th_lds[r][4 * q];
        f32x4 xv = *(const f32x4*)&x1_lds[lrow][4 + 4 * q];
#pragma unroll
        for (int j = 0; j < 4; ++j) {
            float z = (xv[j] - cv[j]) * iv[j];
            acc = fmaf(z, z, acc);
            tdot = fmaf(tv[j], xv[j], tdot);
        }
    }
    float logw = -0.5f * acc;

    // softmax over the 32 rule-lanes of this row
    float m = logw;
#pragma unroll
    for (int off = 16; off >= 1; off >>= 1)
        m = fmaxf(m, __shfl_xor(m, off, 32));
    float ex = __expf(logw - m);
    float s = ex;
#pragma unroll
    for (int off = 16; off >= 1; off >>= 1)
        s += __shfl_xor(s, off, 32);
    float w = ex / (s + EPS);
    w_lds[lrow][r] = w;
    __builtin_nontemporal_store(w, w_out + (size_t)(row0 + lrow) * R + r);

    // y = sum_r w_r * (theta_r . [1,x])
    float yc = w * tdot;
#pragma unroll
    for (int off = 16; off >= 1; off >>= 1)
        yc += __shfl_xor(yc, off, 32);
    if (r == 0) __builtin_nontemporal_store(yc, y_out + row0 + lrow);
    __syncthreads();

    // ---- phase 2: stream Phi as float4 (16 B/lane), fully coalesced ----
    // phi_out base byte offset 4,325,376 and row stride 8320 B are both
    // 128B-aligned; each wave's store covers 1 KB contiguous (full lines).
    for (int k = tid; k < PHI_COLS / 4; k += BLOCK) {
        int e = 4 * k;
        int r0 = (e + 0) / 65, j0 = (e + 0) - r0 * 65;
        int r1 = (e + 1) / 65, j1 = (e + 1) - r1 * 65;
        int r2 = (e + 2) / 65, j2 = (e + 2) - r2 * 65;
        int r3 = (e + 3) / 65, j3 = (e + 3) - r3 * 65;
#pragma unroll
        for (int row = 0; row < ROWS_PER_BLOCK; ++row) {
            f32x4 o;
            o.x = w_lds[row][r0] * x1_lds[row][3 + j0];
            o.y = w_lds[row][r1] * x1_lds[row][3 + j1];
            o.z = w_lds[row][r2] * x1_lds[row][3 + j2];
            o.w = w_lds[row][r3] * x1_lds[row][3 + j3];
            f32x4* dst = (f32x4*)(phi_out + (size_t)(row0 + row) * PHI_COLS) + k;
            __builtin_nontemporal_store(o, dst);
        }
    }
}

extern "C" void kernel_launch(void* const* d_in, const int* in_sizes, int n_in,
                              void* d_out, int out_size, void* d_ws, size_t ws_size,
                              hipStream_t stream) {
    const float* Xz      = (const float*)d_in[0];
    const float* centers = (const float*)d_in[1];
    const float* sigmas  = (const float*)d_in[2];
    const float* theta   = (const float*)d_in[3];

    float* out = (float*)d_out;
    float* y_out   = out;
    float* w_out   = out + N_ROWS;
    float* phi_out = out + N_ROWS + (size_t)N_ROWS * R;

    dim3 grid(N_ROWS / ROWS_PER_BLOCK);
    tsk_kernel<<<grid, BLOCK, 0, stream>>>(Xz, centers, sigmas, theta,
                                           y_out, w_out, phi_out);
}